// Round 14
// baseline (464.890 us; speedup 1.0000x reference)
//
#include <hip/hip_runtime.h>
#include <math.h>

typedef __bf16 bf16;
typedef __attribute__((ext_vector_type(8))) __bf16 bf16x8;
typedef __attribute__((ext_vector_type(4))) __bf16 bf16x4;
typedef __attribute__((ext_vector_type(4))) float f32x4;

#define N_    128
#define CIN   64
#define COUT  64
#define T_    256
#define V_    17
#define K_    3
#define NCH   (N_*COUT)        // 8192
#define TV    (T_*V_)          // 4352

// workspace layout (float offsets; all 16B-aligned)
#define OFF_XBAR  0
#define SZ_XBAR   (NCH*V_)                 // 139264
#define OFF_A     (OFF_XBAR+SZ_XBAR)       // 139264  a[n][c]
#define SZ_A      NCH                      // 8192
#define OFF_WFRAG (OFF_A+SZ_A)             // 147456  12288 bf16 (6144 f32)
#define SZ_WFRAG  6144
#define OFF_ACB   (OFF_WFRAG+SZ_WFRAG)     // 153600  acB: per n 12288 bf16
#define SZ_ACB    (N_*6144)                // 786432 f32 slots
#define OFF_NAB   (OFF_ACB+SZ_ACB)         // 940032  naB: 24576 bf16
#define SZ_NAB    12288

// ---------------- K1: xbar[n,c,v] = mean_t x0[n,c,t,v] ----------------
__global__ __launch_bounds__(272) void k1_xbar(const float* __restrict__ x0,
                                               float* __restrict__ xbar) {
    int nc = blockIdx.x;
    __shared__ float s[1088];
    const f32x4* p = (const f32x4*)(x0 + (size_t)nc * TV);
    int tid = threadIdx.x;
    float a0 = 0.f, a1 = 0.f, a2 = 0.f, a3 = 0.f;
#pragma unroll
    for (int j = 0; j < 4; ++j) {
        f32x4 v = p[tid + 272*j];
        a0 += v[0]; a1 += v[1]; a2 += v[2]; a3 += v[3];
    }
    s[4*tid+0] = a0; s[4*tid+1] = a1; s[4*tid+2] = a2; s[4*tid+3] = a3;
    __syncthreads();
    if (tid < V_) {
        float t = 0.f;
#pragma unroll
        for (int m = 0; m < 64; ++m) t += s[tid + 17*m];
        xbar[nc*V_ + tid] = t * (1.f / (float)T_);
    }
}

// -------- K2F: attention -> acB (per n) + naB (n==0) + wfrag + a_g ----
// grid 256: block = (n = bid>>1, half = bid&1)
__global__ __launch_bounds__(256) void k2f(
    const float* __restrict__ xbar, const float* __restrict__ cw,
    const float* __restrict__ cb,
    const float* __restrict__ spa_w, const float* __restrict__ spa_b,
    const float* __restrict__ mix_w, const float* __restrict__ mix_b,
    const float* __restrict__ A_SE, const float* __restrict__ A_GEME,
    const float* __restrict__ cha_w, const float* __restrict__ gamma,
    unsigned* __restrict__ acb_u, unsigned* __restrict__ nab_u,
    bf16* __restrict__ wfrag, float* __restrict__ a_out) {
    int bid = blockIdx.x;
    int n = bid >> 1, half = bid & 1;
    int tid = threadIdx.x;
    __shared__ float xb[CIN*V_];
    __shared__ float wb[24*64];
    __shared__ float bb[24];
    __shared__ float sw_[289], sb_[17], mw_[289], mb_[17];
    __shared__ float na_s[24*289];
    __shared__ float rsna[24*V_];
    __shared__ float QK[24*V_];
    __shared__ float F[4*12*V_];
    __shared__ float S_[12*289];
    __shared__ float X_[9*289];
    __shared__ float AC[12*289];
    __shared__ float rsac[12*V_];
    __shared__ float psk[192];
    __shared__ float ps[64];

    for (int i = tid; i < CIN*V_; i += 256) xb[i] = xbar[n*CIN*V_ + i];
    for (int i = tid; i < 24*64; i += 256) {
        int o4 = i >> 6, c = i & 63;
        int k = o4 >> 3, jq = o4 & 7;
        int ob = k*64 + (jq >> 1)*16 + (jq & 1)*8;
        float s = 0.f;
#pragma unroll
        for (int c8 = 0; c8 < 8; ++c8) s += cw[(ob + c8)*64 + c];
        wb[i] = s * 0.125f;
    }
    if (tid < 24) {
        int k = tid >> 3, jq = tid & 7;
        int ob = k*64 + (jq >> 1)*16 + (jq & 1)*8;
        float s = 0.f;
#pragma unroll
        for (int c8 = 0; c8 < 8; ++c8) s += cb[ob + c8];
        bb[tid] = s * 0.125f;
    }
    for (int i = tid; i < 289; i += 256) { sw_[i] = spa_w[i]; mw_[i] = mix_w[i]; }
    if (tid < 17) { sb_[tid] = spa_b[tid]; mb_[tid] = mix_b[tid]; }
    for (int i = tid; i < 24*289; i += 256) na_s[i] = A_SE[i] + A_GEME[i];
    __syncthreads();

    for (int i = tid; i < 24*V_; i += 256) {   // rsna
        int kg = i / V_, v = i % V_;
        float s = 0.f;
#pragma unroll
        for (int w = 0; w < V_; ++w) s += na_s[kg*289 + v*17 + w];
        rsna[i] = s;
    }
    for (int i = tid; i < 24*V_; i += 256) {   // QK
        int o4 = i / V_, v = i % V_;
        float s = bb[o4];
        for (int c = 0; c < CIN; ++c) s += xb[c*V_ + v] * wb[o4*64 + c];
        QK[i] = s;
    }
    __syncthreads();

    for (int i = tid; i < 4*12*V_; i += 256) {
        int f = i / (12*V_); int r = i % (12*V_);
        int u = r / V_; int vp = r % V_;
        int k = u >> 2, j = u & 3;
        int q = (f == 1 || f == 2) ? 1 : 0;
        const float* src  = &QK[(k*8 + j*2 + q) * V_];
        const float* wmat = (f <= 1) ? sw_ : mw_;
        const float* bvec = (f <= 1) ? sb_ : mb_;
        float s = bvec[vp];
#pragma unroll
        for (int v = 0; v < V_; ++v) s += src[v] * wmat[vp*V_ + v];
        F[i] = fmaxf(s, 0.f);
    }
    __syncthreads();

    for (int r = tid; r < (12+9)*V_; r += 256) {
        float a; const float* brow; float* orow;
        if (r < 12*V_) {
            int u = r / V_, v = r % V_;
            a = F[0*12*V_ + u*V_ + v];
            brow = &F[1*12*V_ + u*V_];
            orow = &S_[u*289 + v*V_];
        } else {
            int rx = r - 12*V_;
            int xu = rx / V_, v = rx % V_;
            int k = xu / 3, j = xu % 3;
            a = F[2*12*V_ + (k*4 + j)*V_ + v];
            brow = &F[3*12*V_ + (k*4 + j + 1)*V_];
            orow = &X_[xu*289 + v*V_];
        }
        float vals[V_];
        float mx = -1e30f;
#pragma unroll
        for (int w = 0; w < V_; ++w) { vals[w] = a * brow[w]; mx = fmaxf(mx, vals[w]); }
        float sum = 0.f;
#pragma unroll
        for (int w = 0; w < V_; ++w) { vals[w] = expf(vals[w] - mx); sum += vals[w]; }
        float inv = 1.f / sum;
#pragma unroll
        for (int w = 0; w < V_; ++w) orow[w] = vals[w] * inv;
    }
    __syncthreads();

    for (int i = tid; i < 12*289; i += 256) {
        int u = i / 289; int vw = i % 289;
        int k = u >> 2, jj = u & 3;
        int xb3 = k*3;
        float s = 0.5f * S_[i];
        if (jj == 0)      s += 0.25f *  X_[(xb3+0)*289 + vw];
        else if (jj == 1) s += 0.25f * (X_[(xb3+0)*289 + vw] + X_[(xb3+1)*289 + vw]);
        else if (jj == 2) s += 0.25f * (X_[(xb3+1)*289 + vw] + X_[(xb3+2)*289 + vw]);
        else              s += 0.25f *  X_[(xb3+2)*289 + vw];
        AC[i] = s;
    }
    __syncthreads();

    for (int i = tid; i < 12*V_; i += 256) {    // rsac = 0.5*rowsum(AC)
        int u = i / V_, v = i % V_;
        float s = 0.f;
#pragma unroll
        for (int w = 0; w < V_; ++w) s += AC[u*289 + v*17 + w];
        rsac[i] = 0.5f * s;
    }
    __syncthreads();

    // acB: per-n B-tiles [k][jb][nt][lane][jp] u32 ; val = 0.5*AC[k*4+jb][v][w]
    unsigned* acbn = acb_u + (size_t)n * 6144;
    for (int i = tid + half*3072; i < 3072 + half*3072; i += 256) {
        int jp = i & 3, lane = (i >> 2) & 63, nt = (i >> 8) & 1;
        int jb = (i >> 9) & 3, k = i >> 11;
        int w = nt*16 + (lane & 15);
        unsigned short us[2];
#pragma unroll
        for (int jj = 0; jj < 2; ++jj) {
            int v = (lane >> 4)*8 + jp*2 + jj;
            float val = (v < 17 && w < 17) ? 0.5f * AC[(k*4 + jb)*289 + v*17 + w] : 0.f;
            bf16 b = (bf16)val;
            __builtin_memcpy(&us[jj], &b, 2);
        }
        acbn[i] = (unsigned)us[0] | ((unsigned)us[1] << 16);
    }
    // naB: global B-tiles [k][g][nt][lane][jp] u32 (n-independent, n==0 writes)
    if (n == 0) {
        for (int i = tid + half*6144; i < 6144 + half*6144; i += 256) {
            int jp = i & 3, lane = (i >> 2) & 63, nt = (i >> 8) & 1;
            int g = (i >> 9) & 7, k = i >> 12;
            int w = nt*16 + (lane & 15);
            unsigned short us[2];
#pragma unroll
            for (int jj = 0; jj < 2; ++jj) {
                int v = (lane >> 4)*8 + jp*2 + jj;
                float val = (v < 17 && w < 17) ? na_s[(k*8 + g)*289 + v*17 + w] : 0.f;
                bf16 b = (bf16)val;
                __builtin_memcpy(&us[jj], &b, 2);
            }
            nab_u[i] = (unsigned)us[0] | ((unsigned)us[1] << 16);
        }
    }
    if (half) {
        for (int i = tid; i < 12288; i += 256) {
            int j = i & 7, l = (i >> 3) & 63, s = (i >> 9) & 1, ot = i >> 10;
            int o  = ot*16 + (l & 15);
            int ci = s*32 + ((l >> 4)*8) + j;
            wfrag[i] = (bf16)cw[o*64 + ci];
        }
    }
    if (half == 0 && tid < 192) {
        int k = tid >> 6, c = tid & 63;
        float mb[V_];
        float b = cb[k*64 + c];
#pragma unroll
        for (int v = 0; v < V_; ++v) mb[v] = b;
        for (int ci = 0; ci < CIN; ++ci) {
            float w = cw[(k*64 + c)*64 + ci];
#pragma unroll
            for (int v = 0; v < V_; ++v) mb[v] += w * xb[ci*V_ + v];
        }
        int jb = c >> 4, g = c & 7;
        float pool = 0.f;
#pragma unroll
        for (int v = 0; v < V_; ++v)
            pool += mb[v] * (rsac[(k*4 + jb)*V_ + v] + rsna[(k*8 + g)*V_ + v]);
        psk[tid] = pool;
    }
    __syncthreads();
    if (half == 0 && tid < 64) {
        ps[tid] = (psk[tid] + psk[64 + tid] + psk[128 + tid]) * (1.f / 17.f);
    }
    __syncthreads();
    if (half == 0 && tid < 64) {
        int c = tid;
        float pm = ps[c];
        float pl = (c > 0)  ? ps[c-1] : 0.f;
        float pr = (c < 63) ? ps[c+1] : 0.f;
        float cr = cha_w[0]*pl + cha_w[1]*pm + cha_w[2]*pr;
        float sig = 1.f / (1.f + expf(-cr));
        a_out[n*64 + c] = (1.f + sig) * gamma[c] * rsqrtf(1.f + 1e-5f);
    }
}

// -------- K3: persistent (n, quarter), 8 t-tiles, dbuf Xs, masked apply --
// 256 threads = 4 waves; wave w owns channels c = 16w..16w+15 for all k.
// LDS: Ms  [c:64][t:8][40 B] XOR ((c&7)<<3)   @0      (20480)
//      Xs0 [tvp:160][128 B]  XOR ((tvp&7)<<4) @20480  (20480)
//      Xs1 same                               @40960  (20480)
// CORRECTNESS: the apply A-operand's v>=17 elements are zeroed IN REGISTERS
// (mask by lg), so don't-care LDS bytes (incl. epilogue float scribble, which
// can alias to bf16-NaN patterns) never reach the MFMA. R13's failure was
// NaN x 0 = NaN from exactly those bytes.
#define STAGE_LOAD(t0v)                                                     \
    { const float* xsrc = xn + (size_t)(t0v)*V_;                            \
      _Pragma("unroll")                                                     \
      for (int g = 0; g < 5; ++g) {                                         \
          int i = tid + 256*g;                                              \
          int tvp = i % 160, ci8 = i / 160;                                 \
          int t = tvp/20, v = tvp%20;                                       \
          const float* p = xsrc + (size_t)(ci8*8)*TV + t*V_ + v;            \
          bool ok = (v < 17);                                               \
          _Pragma("unroll")                                                 \
          for (int jj = 0; jj < 8; ++jj)                                    \
              rx[g*8+jj] = ok ? p[jj*TV] : 0.f;                             \
      } }

#define STAGE_WRITE(dstp)                                                   \
    { _Pragma("unroll")                                                     \
      for (int g = 0; g < 5; ++g) {                                         \
          int i = tid + 256*g;                                              \
          int tvp = i % 160, ci8 = i / 160;                                 \
          bf16x8 bv;                                                        \
          _Pragma("unroll")                                                 \
          for (int jj = 0; jj < 8; ++jj) bv[jj] = (bf16)rx[g*8+jj];         \
          *(bf16x8*)((dstp) + ((tvp*128 + ci8*16) ^ ((tvp & 7) << 4))) = bv;\
      } }

__global__ __launch_bounds__(256, 2) void k3_main(
    const float* __restrict__ x0, const float* __restrict__ cb,
    const bf16* __restrict__ wfrag, const bf16* __restrict__ acb,
    const bf16* __restrict__ nab, const float* __restrict__ a_g,
    const float* __restrict__ beta, float* __restrict__ out) {
    __shared__ __align__(16) unsigned char smem[61440];
    unsigned char* Ms  = smem;
    unsigned char* Xs0 = smem + 20480;
    unsigned char* Xs1 = smem + 40960;

    int bid = blockIdx.x;
    int orig = (bid & 7)*64 + (bid >> 3);       // XCD swizzle (512%8==0)
    int n  = orig >> 2;
    int tg = orig & 3;                           // quarter: t-tiles tg*8..+7
    int tid = threadIdx.x, lane = tid & 63, wave = tid >> 6;
    int cbw = wave * 16;
    int l15 = lane & 15, lg = lane >> 4;
    int cconv = cbw + l15;
    int wsz = (l15 & 7) << 3;                    // (cconv&7)<<3
    int ta = l15 & 7;
    int ch = l15 >> 3;

    // A-operand sanitization masks: am elements cover v = lg*8 .. lg*8+7.
    // lg<=1: all real. lg==2: keep v16 (elem 0) only. lg==3: all v>=24 -> 0.
    unsigned mA = (lg < 2) ? 0xFFFFFFFFu : ((lg == 2) ? 0x0000FFFFu : 0u);
    unsigned mB = (lg < 2) ? 0xFFFFFFFFu : 0u;

    const float* xn = x0 + (size_t)n * (CIN*TV);
    const bf16* acbn = acb + (size_t)n * 12288;

    // ---- hoisted tile-invariants ----
    bf16x8 wf[3][2], acf[3][2];
    f32x4 dinit[3];
#pragma unroll
    for (int k = 0; k < 3; ++k) {
        const bf16* wfp = wfrag + (size_t)((k*4 + wave)*2) * 512;
        wf[k][0] = *(const bf16x8*)(wfp + lane*8);
        wf[k][1] = *(const bf16x8*)(wfp + 512 + lane*8);
        const bf16* act = acbn + (size_t)(k*4 + wave) * 1024;
        acf[k][0] = *(const bf16x8*)(act + lane*8);
        acf[k][1] = *(const bf16x8*)(act + 512 + lane*8);
        float b = cb[k*64 + cconv];
        dinit[k][0] = b; dinit[k][1] = b; dinit[k][2] = b; dinit[k][3] = b;
    }
    int chi = lg >> 1;
    int tb = (lg & 1) * 4;
    float av[8], bvv[8];
#pragma unroll
    for (int p = 0; p < 8; ++p) {
        int c = cbw + p + 8*chi;
        av[p] = a_g[n*64 + c];
        bvv[p] = beta[c];
    }
    // k-invariant Ms write offsets (includes the XOR)
    int mo[10];
#pragma unroll
    for (int mt = 0; mt < 10; ++mt) {
        int tvpd = mt*16 + lg*4;
        int td = tvpd / 20, v0 = tvpd % 20;     // v0 in {0,4,8,12,16}
        mo[mt] = ((cconv*320 + td*40 + v0*2) ^ wsz);
    }

    float rx[40];
    STAGE_LOAD(tg*64);
    STAGE_WRITE(Xs0);
    __syncthreads();

    int buf = 0;
#pragma unroll 1
    for (int j = 0; j < 8; ++j) {
        int t0j = tg*64 + j*8;
        if (j < 7) STAGE_LOAD(t0j + 8);          // issue next tile EARLY
        unsigned char* Xc = buf ? Xs1 : Xs0;
        unsigned char* Xn2 = buf ? Xs0 : Xs1;

        f32x4 acc[8][2] = {};
#pragma unroll
        for (int k = 0; k < 3; ++k) {
            // conv: this wave's 16 channels, 160 tvp rows (bias in C-init)
#pragma unroll
            for (int mt = 0; mt < 10; ++mt) {
                int tvp = mt*16 + l15;
                int arow = tvp*128, sw = (tvp & 7) << 4;
                bf16x8 a0 = *(const bf16x8*)(Xc + ((arow + lg*16) ^ sw));
                bf16x8 a1 = *(const bf16x8*)(Xc + ((arow + 64 + lg*16) ^ sw));
                f32x4 d = dinit[k];
                d = __builtin_amdgcn_mfma_f32_16x16x32_bf16(a0, wf[k][0], d, 0, 0, 0);
                d = __builtin_amdgcn_mfma_f32_16x16x32_bf16(a1, wf[k][1], d, 0, 0, 0);
                bf16x4 mv;
                mv[0] = (bf16)d[0]; mv[1] = (bf16)d[1];
                mv[2] = (bf16)d[2]; mv[3] = (bf16)d[3];
                *(bf16x4*)(Ms + mo[mt]) = mv;
            }
            // apply: acc[p] += am*acB[k][wave] + am*naB[k][p], am sanitized
#pragma unroll
            for (int p = 0; p < 8; ++p) {
                int ca = cbw + p + 8*ch;
                int csw = p << 3;               // (ca&7)<<3
                int abase = ca*320 + ta*40 + lg*16;
                union { bf16x4 b; unsigned u[2]; } lo, hi;
                lo.b = *(const bf16x4*)(Ms + (abase ^ csw));
                hi.b = *(const bf16x4*)(Ms + ((abase + 8) ^ csw));
                lo.u[0] &= mA; lo.u[1] &= mB;
                hi.u[0] &= mB; hi.u[1] &= mB;
                bf16x8 am = __builtin_shufflevector(lo.b, hi.b, 0, 1, 2, 3, 4, 5, 6, 7);
                const bf16* nbt = nab + (size_t)(k*8 + p) * 1024;
                bf16x8 nf0 = *(const bf16x8*)(nbt + lane*8);
                bf16x8 nf1 = *(const bf16x8*)(nbt + 512 + lane*8);
                acc[p][0] = __builtin_amdgcn_mfma_f32_16x16x32_bf16(am, acf[k][0], acc[p][0], 0, 0, 0);
                acc[p][1] = __builtin_amdgcn_mfma_f32_16x16x32_bf16(am, acf[k][1], acc[p][1], 0, 0, 0);
                acc[p][0] = __builtin_amdgcn_mfma_f32_16x16x32_bf16(am, nf0, acc[p][0], 0, 0, 0);
                acc[p][1] = __builtin_amdgcn_mfma_f32_16x16x32_bf16(am, nf1, acc[p][1], 0, 0, 0);
            }
        }

        __syncthreads();   // B1: all conv/apply LDS reads done

        // ---- wave-private epilogue: ys in own dead Ms/Xc region ----
#pragma unroll
        for (int p = 0; p < 8; ++p) {
            int cl = p + 8*chi;
            float* yr = (float*)((cl < 9 ? Ms + wave*5120 + cl*552
                                         : Xc + wave*5120 + (cl-9)*552));
#pragma unroll
            for (int i = 0; i < 4; ++i)
                yr[(tb + i)*17 + l15] = av[p]*acc[p][0][i] + bvv[p];
            if (l15 == 0) {
#pragma unroll
                for (int i = 0; i < 4; ++i)
                    yr[(tb + i)*17 + 16] = av[p]*acc[p][1][i] + bvv[p];
            }
        }
        // own-wave coalesced read -> global (own region; no barrier needed)
        {
            float* outn = out + (size_t)n * (COUT*TV) + (size_t)t0j * V_;
            const float* x0n = xn + (size_t)t0j * V_;
            for (int ii = lane; ii < 544; ii += 64) {
                int cl = ii / 34, q = ii % 34;
                const float* yr = (const float*)((cl < 9 ? Ms + wave*5120 + cl*552
                                                         : Xc + wave*5120 + (cl-9)*552));
                f32x4 yv = *(const f32x4*)(yr + q*4);
                size_t gidx = (size_t)(cbw + cl)*TV + q*4;
                f32x4 xv = *(const f32x4*)(x0n + gidx);
                f32x4 o;
                o[0] = fmaxf(yv[0] + xv[0], 0.f);
                o[1] = fmaxf(yv[1] + xv[1], 0.f);
                o[2] = fmaxf(yv[2] + xv[2], 0.f);
                o[3] = fmaxf(yv[3] + xv[3], 0.f);
                *(f32x4*)(outn + gidx) = o;
            }
        }

        if (j < 7) STAGE_WRITE(Xn2);   // write LATE into idle buffer
        __syncthreads();               // B2: Xn ready; ys regions free
        buf ^= 1;
    }
}

extern "C" void kernel_launch(void* const* d_in, const int* in_sizes, int n_in,
                              void* d_out, int out_size, void* d_ws, size_t ws_size,
                              hipStream_t stream) {
    const float* x0     = (const float*)d_in[0];
    const float* conv_w = (const float*)d_in[1];
    const float* conv_b = (const float*)d_in[2];
    const float* spa_w  = (const float*)d_in[3];
    const float* spa_b  = (const float*)d_in[4];
    const float* mix_w  = (const float*)d_in[5];
    const float* mix_b  = (const float*)d_in[6];
    const float* A_GEME = (const float*)d_in[7];
    const float* A_SE   = (const float*)d_in[8];
    const float* cha_w  = (const float*)d_in[9];
    const float* gamma  = (const float*)d_in[10];
    const float* beta   = (const float*)d_in[11];

    float* ws    = (float*)d_ws;
    float* xbar  = ws + OFF_XBAR;
    float* a_g   = ws + OFF_A;
    bf16*  wfrag = (bf16*)(ws + OFF_WFRAG);
    bf16*  acb   = (bf16*)(ws + OFF_ACB);
    bf16*  nab   = (bf16*)(ws + OFF_NAB);
    float* y     = (float*)d_out;

    k1_xbar<<<NCH, 272, 0, stream>>>(x0, xbar);
    k2f<<<256, 256, 0, stream>>>(xbar, conv_w, conv_b, spa_w, spa_b,
                                 mix_w, mix_b, A_SE, A_GEME, cha_w, gamma,
                                 (unsigned*)acb, (unsigned*)nab, wfrag, a_g);
    k3_main<<<512, 256, 0, stream>>>(x0, conv_b, wfrag, acb, nab, a_g, beta, y);
}

// Round 15
// 167.507 us; speedup vs baseline: 2.7753x; 2.7753x over previous
//
#include <hip/hip_runtime.h>
#include <math.h>

typedef __bf16 bf16;
typedef __attribute__((ext_vector_type(8))) __bf16 bf16x8;
typedef __attribute__((ext_vector_type(4))) __bf16 bf16x4;
typedef __attribute__((ext_vector_type(4))) float f32x4;

#define N_    128
#define CIN   64
#define COUT  64
#define T_    256
#define V_    17
#define K_    3
#define NCH   (N_*COUT)        // 8192
#define TV    (T_*V_)          // 4352

// workspace layout (float offsets; all 16B-aligned)
#define OFF_XBAR  0
#define SZ_XBAR   (NCH*V_)                 // 139264
#define OFF_A     (OFF_XBAR+SZ_XBAR)       // 139264  a[n][c]
#define SZ_A      NCH                      // 8192
#define OFF_WFRAG (OFF_A+SZ_A)             // 147456  12288 bf16 (6144 f32)
#define SZ_WFRAG  6144
#define OFF_ACB   (OFF_WFRAG+SZ_WFRAG)     // 153600  acB: per n 12288 bf16
#define SZ_ACB    (N_*6144)                // 786432 f32 slots
#define OFF_NAB   (OFF_ACB+SZ_ACB)         // 940032  naB: 24576 bf16
#define SZ_NAB    12288

// ---------------- K1: xbar[n,c,v] = mean_t x0[n,c,t,v] ----------------
__global__ __launch_bounds__(272) void k1_xbar(const float* __restrict__ x0,
                                               float* __restrict__ xbar) {
    int nc = blockIdx.x;
    __shared__ float s[1088];
    const f32x4* p = (const f32x4*)(x0 + (size_t)nc * TV);
    int tid = threadIdx.x;
    float a0 = 0.f, a1 = 0.f, a2 = 0.f, a3 = 0.f;
#pragma unroll
    for (int j = 0; j < 4; ++j) {
        f32x4 v = p[tid + 272*j];
        a0 += v[0]; a1 += v[1]; a2 += v[2]; a3 += v[3];
    }
    s[4*tid+0] = a0; s[4*tid+1] = a1; s[4*tid+2] = a2; s[4*tid+3] = a3;
    __syncthreads();
    if (tid < V_) {
        float t = 0.f;
#pragma unroll
        for (int m = 0; m < 64; ++m) t += s[tid + 17*m];
        xbar[nc*V_ + tid] = t * (1.f / (float)T_);
    }
}

// -------- K2F: attention -> acB (per n) + naB (n==0) + wfrag + a_g ----
// grid 256: block = (n = bid>>1, half = bid&1)
__global__ __launch_bounds__(256) void k2f(
    const float* __restrict__ xbar, const float* __restrict__ cw,
    const float* __restrict__ cb,
    const float* __restrict__ spa_w, const float* __restrict__ spa_b,
    const float* __restrict__ mix_w, const float* __restrict__ mix_b,
    const float* __restrict__ A_SE, const float* __restrict__ A_GEME,
    const float* __restrict__ cha_w, const float* __restrict__ gamma,
    unsigned* __restrict__ acb_u, unsigned* __restrict__ nab_u,
    bf16* __restrict__ wfrag, float* __restrict__ a_out) {
    int bid = blockIdx.x;
    int n = bid >> 1, half = bid & 1;
    int tid = threadIdx.x;
    __shared__ float xb[CIN*V_];
    __shared__ float wb[24*64];
    __shared__ float bb[24];
    __shared__ float sw_[289], sb_[17], mw_[289], mb_[17];
    __shared__ float na_s[24*289];
    __shared__ float rsna[24*V_];
    __shared__ float QK[24*V_];
    __shared__ float F[4*12*V_];
    __shared__ float S_[12*289];
    __shared__ float X_[9*289];
    __shared__ float AC[12*289];
    __shared__ float rsac[12*V_];
    __shared__ float psk[192];
    __shared__ float ps[64];

    for (int i = tid; i < CIN*V_; i += 256) xb[i] = xbar[n*CIN*V_ + i];
    for (int i = tid; i < 24*64; i += 256) {
        int o4 = i >> 6, c = i & 63;
        int k = o4 >> 3, jq = o4 & 7;
        int ob = k*64 + (jq >> 1)*16 + (jq & 1)*8;
        float s = 0.f;
#pragma unroll
        for (int c8 = 0; c8 < 8; ++c8) s += cw[(ob + c8)*64 + c];
        wb[i] = s * 0.125f;
    }
    if (tid < 24) {
        int k = tid >> 3, jq = tid & 7;
        int ob = k*64 + (jq >> 1)*16 + (jq & 1)*8;
        float s = 0.f;
#pragma unroll
        for (int c8 = 0; c8 < 8; ++c8) s += cb[ob + c8];
        bb[tid] = s * 0.125f;
    }
    for (int i = tid; i < 289; i += 256) { sw_[i] = spa_w[i]; mw_[i] = mix_w[i]; }
    if (tid < 17) { sb_[tid] = spa_b[tid]; mb_[tid] = mix_b[tid]; }
    for (int i = tid; i < 24*289; i += 256) na_s[i] = A_SE[i] + A_GEME[i];
    __syncthreads();

    for (int i = tid; i < 24*V_; i += 256) {   // rsna
        int kg = i / V_, v = i % V_;
        float s = 0.f;
#pragma unroll
        for (int w = 0; w < V_; ++w) s += na_s[kg*289 + v*17 + w];
        rsna[i] = s;
    }
    for (int i = tid; i < 24*V_; i += 256) {   // QK
        int o4 = i / V_, v = i % V_;
        float s = bb[o4];
        for (int c = 0; c < CIN; ++c) s += xb[c*V_ + v] * wb[o4*64 + c];
        QK[i] = s;
    }
    __syncthreads();

    for (int i = tid; i < 4*12*V_; i += 256) {
        int f = i / (12*V_); int r = i % (12*V_);
        int u = r / V_; int vp = r % V_;
        int k = u >> 2, j = u & 3;
        int q = (f == 1 || f == 2) ? 1 : 0;
        const float* src  = &QK[(k*8 + j*2 + q) * V_];
        const float* wmat = (f <= 1) ? sw_ : mw_;
        const float* bvec = (f <= 1) ? sb_ : mb_;
        float s = bvec[vp];
#pragma unroll
        for (int v = 0; v < V_; ++v) s += src[v] * wmat[vp*V_ + v];
        F[i] = fmaxf(s, 0.f);
    }
    __syncthreads();

    for (int r = tid; r < (12+9)*V_; r += 256) {
        float a; const float* brow; float* orow;
        if (r < 12*V_) {
            int u = r / V_, v = r % V_;
            a = F[0*12*V_ + u*V_ + v];
            brow = &F[1*12*V_ + u*V_];
            orow = &S_[u*289 + v*V_];
        } else {
            int rx = r - 12*V_;
            int xu = rx / V_, v = rx % V_;
            int k = xu / 3, j = xu % 3;
            a = F[2*12*V_ + (k*4 + j)*V_ + v];
            brow = &F[3*12*V_ + (k*4 + j + 1)*V_];
            orow = &X_[xu*289 + v*V_];
        }
        float vals[V_];
        float mx = -1e30f;
#pragma unroll
        for (int w = 0; w < V_; ++w) { vals[w] = a * brow[w]; mx = fmaxf(mx, vals[w]); }
        float sum = 0.f;
#pragma unroll
        for (int w = 0; w < V_; ++w) { vals[w] = expf(vals[w] - mx); sum += vals[w]; }
        float inv = 1.f / sum;
#pragma unroll
        for (int w = 0; w < V_; ++w) orow[w] = vals[w] * inv;
    }
    __syncthreads();

    for (int i = tid; i < 12*289; i += 256) {
        int u = i / 289; int vw = i % 289;
        int k = u >> 2, jj = u & 3;
        int xb3 = k*3;
        float s = 0.5f * S_[i];
        if (jj == 0)      s += 0.25f *  X_[(xb3+0)*289 + vw];
        else if (jj == 1) s += 0.25f * (X_[(xb3+0)*289 + vw] + X_[(xb3+1)*289 + vw]);
        else if (jj == 2) s += 0.25f * (X_[(xb3+1)*289 + vw] + X_[(xb3+2)*289 + vw]);
        else              s += 0.25f *  X_[(xb3+2)*289 + vw];
        AC[i] = s;
    }
    __syncthreads();

    for (int i = tid; i < 12*V_; i += 256) {    // rsac = 0.5*rowsum(AC)
        int u = i / V_, v = i % V_;
        float s = 0.f;
#pragma unroll
        for (int w = 0; w < V_; ++w) s += AC[u*289 + v*17 + w];
        rsac[i] = 0.5f * s;
    }
    __syncthreads();

    // acB: per-n B-tiles [k][jb][nt][lane][jp] u32 ; val = 0.5*AC[k*4+jb][v][w]
    unsigned* acbn = acb_u + (size_t)n * 6144;
    for (int i = tid + half*3072; i < 3072 + half*3072; i += 256) {
        int jp = i & 3, lane = (i >> 2) & 63, nt = (i >> 8) & 1;
        int jb = (i >> 9) & 3, k = i >> 11;
        int w = nt*16 + (lane & 15);
        unsigned short us[2];
#pragma unroll
        for (int jj = 0; jj < 2; ++jj) {
            int v = (lane >> 4)*8 + jp*2 + jj;
            float val = (v < 17 && w < 17) ? 0.5f * AC[(k*4 + jb)*289 + v*17 + w] : 0.f;
            bf16 b = (bf16)val;
            __builtin_memcpy(&us[jj], &b, 2);
        }
        acbn[i] = (unsigned)us[0] | ((unsigned)us[1] << 16);
    }
    // naB: global B-tiles [k][g][nt][lane][jp] u32 (n-independent, n==0 writes)
    if (n == 0) {
        for (int i = tid + half*6144; i < 6144 + half*6144; i += 256) {
            int jp = i & 3, lane = (i >> 2) & 63, nt = (i >> 8) & 1;
            int g = (i >> 9) & 7, k = i >> 12;
            int w = nt*16 + (lane & 15);
            unsigned short us[2];
#pragma unroll
            for (int jj = 0; jj < 2; ++jj) {
                int v = (lane >> 4)*8 + jp*2 + jj;
                float val = (v < 17 && w < 17) ? na_s[(k*8 + g)*289 + v*17 + w] : 0.f;
                bf16 b = (bf16)val;
                __builtin_memcpy(&us[jj], &b, 2);
            }
            nab_u[i] = (unsigned)us[0] | ((unsigned)us[1] << 16);
        }
    }
    if (half) {
        for (int i = tid; i < 12288; i += 256) {
            int j = i & 7, l = (i >> 3) & 63, s = (i >> 9) & 1, ot = i >> 10;
            int o  = ot*16 + (l & 15);
            int ci = s*32 + ((l >> 4)*8) + j;
            wfrag[i] = (bf16)cw[o*64 + ci];
        }
    }
    if (half == 0 && tid < 192) {
        int k = tid >> 6, c = tid & 63;
        float mb[V_];
        float b = cb[k*64 + c];
#pragma unroll
        for (int v = 0; v < V_; ++v) mb[v] = b;
        for (int ci = 0; ci < CIN; ++ci) {
            float w = cw[(k*64 + c)*64 + ci];
#pragma unroll
            for (int v = 0; v < V_; ++v) mb[v] += w * xb[ci*V_ + v];
        }
        int jb = c >> 4, g = c & 7;
        float pool = 0.f;
#pragma unroll
        for (int v = 0; v < V_; ++v)
            pool += mb[v] * (rsac[(k*4 + jb)*V_ + v] + rsna[(k*8 + g)*V_ + v]);
        psk[tid] = pool;
    }
    __syncthreads();
    if (half == 0 && tid < 64) {
        ps[tid] = (psk[tid] + psk[64 + tid] + psk[128 + tid]) * (1.f / 17.f);
    }
    __syncthreads();
    if (half == 0 && tid < 64) {
        int c = tid;
        float pm = ps[c];
        float pl = (c > 0)  ? ps[c-1] : 0.f;
        float pr = (c < 63) ? ps[c+1] : 0.f;
        float cr = cha_w[0]*pl + cha_w[1]*pm + cha_w[2]*pr;
        float sig = 1.f / (1.f + expf(-cr));
        a_out[n*64 + c] = (1.f + sig) * gamma[c] * rsqrtf(1.f + 1e-5f);
    }
}

// -------- K3: R7 skeleton; apply B-tiles = acB (L2-hot) + naB (L1-hot) --
// block: (n, t0 tile of 8). 256 threads = 4 waves. Wave w owns c = w*16..+15.
// For wave w, channel c = 16w + p + 8ch: jb = c>>4 = w, g = c&7 = p.
// So  Af_tile(k,w,p) = acB[k][w] + naB[k][p]  -> two MFMAs with shared tiles.
// LDS: Ms [c:64][t:8][40 B] XOR ((c&7)<<3) = 20480 ; Xs [tvp:160][128 B] = 20480.
__global__ __launch_bounds__(256, 3) void k3_main(
    const float* __restrict__ x0, const float* __restrict__ cb,
    const bf16* __restrict__ wfrag, const bf16* __restrict__ acb,
    const bf16* __restrict__ nab, const float* __restrict__ a_g,
    const float* __restrict__ beta, float* __restrict__ out) {
    int bid = blockIdx.x;
    int orig = (bid & 7)*512 + (bid >> 3);      // XCD-chunked swizzle (4096%8==0)
    int n = orig >> 5;
    int t0 = (orig & 31) * 8;
    int tid = threadIdx.x, lane = tid & 63, wave = tid >> 6;

    __shared__ __align__(16) unsigned char smem[40960];
    unsigned char* Ms = smem;
    unsigned char* Xs = smem + 20480;

    int cbw = wave * 16;
    int l15 = lane & 15, lg = lane >> 4;

    // stage Xs: transpose on the global-read side; one b64 LDS write per iter.
    const float* xsrc = x0 + (size_t)n * (CIN*TV) + (size_t)t0 * V_;
    for (int i = tid; i < 2560; i += 256) {
        int tvp = i % 160;
        int ci4 = i / 160;
        int t = tvp / 20, v = tvp % 20;
        bf16x4 bv = {(bf16)0.f, (bf16)0.f, (bf16)0.f, (bf16)0.f};
        if (v < 17) {
            const float* p = xsrc + (size_t)(ci4*4)*TV + t*V_ + v;
            bv[0] = (bf16)p[0];
            bv[1] = (bf16)p[TV];
            bv[2] = (bf16)p[2*TV];
            bv[3] = (bf16)p[3*TV];
        }
        *(bf16x4*)(Xs + ((tvp*128 + ci4*8) ^ ((tvp & 7) << 4))) = bv;
    }

    int cconv = cbw + l15;
    int wsz = (l15 & 7) << 3;           // (cconv&7)<<3
    __syncthreads();   // Xs ready

    f32x4 acc[8][2] = {};
    const bf16* acbn = acb + (size_t)n * 12288;
    int ta = l15 & 7;
    int ch = l15 >> 3;

#pragma unroll
    for (int k = 0; k < 3; ++k) {
        const bf16* wfp = wfrag + (size_t)((k*4 + wave)*2) * 512;
        bf16x8 wf0 = *(const bf16x8*)(wfp + lane*8);
        bf16x8 wf1 = *(const bf16x8*)(wfp + 512 + lane*8);
        float bias = cb[k*64 + cconv];
        // acB tile for (k, jb=wave): shared across all p (L2-hot, 2 loads)
        const bf16* act = acbn + (size_t)(k*4 + wave) * 1024;
        bf16x8 acf0 = *(const bf16x8*)(act + lane*8);
        bf16x8 acf1 = *(const bf16x8*)(act + 512 + lane*8);
        // ---- conv: m for this wave's 16 channels, all 160 tvp rows ----
#pragma unroll
        for (int mt = 0; mt < 10; ++mt) {
            int tvp = mt*16 + l15;
            int arow = tvp*128, sw = (tvp & 7) << 4;
            bf16x8 a0 = *(const bf16x8*)(Xs + ((arow + lg*16) ^ sw));
            bf16x8 a1 = *(const bf16x8*)(Xs + ((arow + 64 + lg*16) ^ sw));
            f32x4 d = {0.f, 0.f, 0.f, 0.f};
            d = __builtin_amdgcn_mfma_f32_16x16x32_bf16(a0, wf0, d, 0, 0, 0);
            d = __builtin_amdgcn_mfma_f32_16x16x32_bf16(a1, wf1, d, 0, 0, 0);
            int tvpd = mt*16 + lg*4;
            int td = tvpd / 20, v0 = tvpd % 20;   // v0 in {0,4,8,12,16}
            bf16x4 mv;
            mv[0] = (bf16)(d[0] + bias);
            mv[1] = (bf16)(d[1] + bias);
            mv[2] = (bf16)(d[2] + bias);
            mv[3] = (bf16)(d[3] + bias);
            int mo = (cconv*320 + td*40 + v0*2) ^ wsz;
            *(bf16x4*)(Ms + mo) = mv;
        }
        // ---- apply: acc[p] += am*acB[k][wave] + am*naB[k][p] ----
#pragma unroll
        for (int p = 0; p < 8; ++p) {
            int ca = cbw + p + 8*ch;
            int csw = p << 3;               // (ca&7)<<3
            int abase = ca*320 + ta*40 + lg*16;
            bf16x4 amlo = *(const bf16x4*)(Ms + (abase ^ csw));
            bf16x4 amhi = *(const bf16x4*)(Ms + ((abase + 8) ^ csw));
            bf16x8 am = __builtin_shufflevector(amlo, amhi, 0, 1, 2, 3, 4, 5, 6, 7);
            const bf16* nbt = nab + (size_t)(k*8 + p) * 1024;
            bf16x8 nf0 = *(const bf16x8*)(nbt + lane*8);
            bf16x8 nf1 = *(const bf16x8*)(nbt + 512 + lane*8);
            acc[p][0] = __builtin_amdgcn_mfma_f32_16x16x32_bf16(am, acf0, acc[p][0], 0, 0, 0);
            acc[p][1] = __builtin_amdgcn_mfma_f32_16x16x32_bf16(am, acf1, acc[p][1], 0, 0, 0);
            acc[p][0] = __builtin_amdgcn_mfma_f32_16x16x32_bf16(am, nf0, acc[p][0], 0, 0, 0);
            acc[p][1] = __builtin_amdgcn_mfma_f32_16x16x32_bf16(am, nf1, acc[p][1], 0, 0, 0);
        }
    }

    // ---- staged epilogue: ys = a*y + beta in LDS, then coalesced pass ----
    __syncthreads();           // all waves done with Ms/Xs
    float* ys = (float*)smem;  // [c][138]
    const float* a_row = a_g + n*64;
    int chi = lg >> 1;
    int tb = (lg & 1) * 4;
#pragma unroll
    for (int p = 0; p < 8; ++p) {
        int c = cbw + p + 8*chi;
        float ac = a_row[c];
        float bc = beta[c];
        float* yr = ys + c*138;
#pragma unroll
        for (int i = 0; i < 4; ++i)
            yr[(tb + i)*17 + l15] = ac*acc[p][0][i] + bc;
        if (l15 == 0) {
#pragma unroll
            for (int i = 0; i < 4; ++i)
                yr[(tb + i)*17 + 16] = ac*acc[p][1][i] + bc;
        }
    }
    __syncthreads();

    float* outn = out + (size_t)n * (COUT*TV) + (size_t)t0 * V_;
    const float* x0n = x0 + (size_t)n * (COUT*TV) + (size_t)t0 * V_;
    for (int ii = tid; ii < 2176; ii += 256) {
        int cc = ii / 34, q = ii % 34;
        f32x4 yv = *(const f32x4*)&ys[cc*138 + q*4];
        f32x4 xv = *(const f32x4*)(x0n + (size_t)cc*TV + q*4);
        f32x4 o;
        o[0] = fmaxf(yv[0] + xv[0], 0.f);
        o[1] = fmaxf(yv[1] + xv[1], 0.f);
        o[2] = fmaxf(yv[2] + xv[2], 0.f);
        o[3] = fmaxf(yv[3] + xv[3], 0.f);
        *(f32x4*)(outn + (size_t)cc*TV + q*4) = o;
    }
}

extern "C" void kernel_launch(void* const* d_in, const int* in_sizes, int n_in,
                              void* d_out, int out_size, void* d_ws, size_t ws_size,
                              hipStream_t stream) {
    const float* x0     = (const float*)d_in[0];
    const float* conv_w = (const float*)d_in[1];
    const float* conv_b = (const float*)d_in[2];
    const float* spa_w  = (const float*)d_in[3];
    const float* spa_b  = (const float*)d_in[4];
    const float* mix_w  = (const float*)d_in[5];
    const float* mix_b  = (const float*)d_in[6];
    const float* A_GEME = (const float*)d_in[7];
    const float* A_SE   = (const float*)d_in[8];
    const float* cha_w  = (const float*)d_in[9];
    const float* gamma  = (const float*)d_in[10];
    const float* beta   = (const float*)d_in[11];

    float* ws    = (float*)d_ws;
    float* xbar  = ws + OFF_XBAR;
    float* a_g   = ws + OFF_A;
    bf16*  wfrag = (bf16*)(ws + OFF_WFRAG);
    bf16*  acb   = (bf16*)(ws + OFF_ACB);
    bf16*  nab   = (bf16*)(ws + OFF_NAB);
    float* y     = (float*)d_out;

    k1_xbar<<<NCH, 272, 0, stream>>>(x0, xbar);
    k2f<<<256, 256, 0, stream>>>(xbar, conv_w, conv_b, spa_w, spa_b,
                                 mix_w, mix_b, A_SE, A_GEME, cha_w, gamma,
                                 (unsigned*)acb, (unsigned*)nab, wfrag, a_g);
    k3_main<<<4096, 256, 0, stream>>>(x0, conv_b, wfrag, acb, nab, a_g, beta, y);
}